// Round 3
// baseline (1316.804 us; speedup 1.0000x reference)
//
#include <hip/hip_runtime.h>

// ---------------------------------------------------------------------------
// MetNet-3 BlockAttention, fused per-window MFMA kernel for gfx950.
// R6 = R5 resubmit (container infra failure, no counters) + LDS alignment
// hardening: every __shared__ array read via ds_read_b64/b128 is __align__(16)
// (u16 arrays are otherwise only 2B-aligned; assume_aligned asserts, doesn't
// create).  Semantics identical to R5:
//  - Phase A (QKV GEMM+LN+norm) for head h+1 software-pipelined under B/C/D
//    of head h (register-resident; LDS stores moved to post-barrier slot).
//  - Vectorized per-head LDS reads: q/k pitch 20 (2x ds_read_b64, quads 2-3
//    register zeros), p/vt pitch 64 + XOR row-swizzle (ds_read_b128),
//    oh pitch 40 (ds_read_b128).
//  - Softmax: no max-subtraction (cosine attn bounds |s|<=~1.1); 1/sum
//    deferred to post-PV scale; rel-bias prefetched one head ahead, fed as
//    MFMA C-init.
//  - Field-swap block swizzle: 8 windows sharing each 128B output line get
//    the same XCD and dispatch within 64 slots (write-merge in L2).
//  - LDS ~54 KB -> 3 WG/CU.
// ---------------------------------------------------------------------------

#define WSZ 8
#define LTOK 64
#define NH 16
#define CCH 256
#define WW2 256
#define HWP 65536          // H*W
#define NWIN 2048          // 2 * 32 * 32 windows

#define TP 258             // sm_t pitch (elements)
#define QP3 20             // sm_q / sm_k pitch (16 data cols, b64-aligned rows)
#define VP3 64             // sm_vt pitch (XOR row-swizzled)
#define PP3 64             // sm_p pitch (XOR row-swizzled)
#define OP3 40             // sm_oh pitch (b128-aligned rows)

typedef __bf16 bf16x8 __attribute__((ext_vector_type(8)));
typedef __bf16 bf16x4 __attribute__((ext_vector_type(4)));
typedef float  f32x4  __attribute__((ext_vector_type(4)));
typedef unsigned short u16;
typedef unsigned long long ull;
typedef uint4  __attribute__((may_alias)) uint4_a;
typedef float4 __attribute__((may_alias)) float4_a;
typedef ull    __attribute__((may_alias)) ull_a;

__device__ __forceinline__ float b2f(u16 u) {
    return (float)__builtin_bit_cast(__bf16, u);
}
__device__ __forceinline__ u16 f2b(float f) {
    return __builtin_bit_cast(u16, (__bf16)f);
}
// dtype-adaptive scalar load of logical element idx
__device__ __forceinline__ float gload(const void* p, int idx, int isf32) {
    return isf32 ? ((const float*)p)[idx] : b2f(((const u16*)p)[idx]);
}
// two ds_read_b64 -> bf16x8 (8B-aligned rows, pitch 20)
__device__ __forceinline__ bf16x8 ld_qk(const u16* p) {
    ull lo = *(const ull_a*)p, hi = *(const ull_a*)(p + 4);
    bf16x4 a = __builtin_bit_cast(bf16x4, lo);
    bf16x4 b = __builtin_bit_cast(bf16x4, hi);
    return bf16x8{a[0], a[1], a[2], a[3], b[0], b[1], b[2], b[3]};
}
// one ds_read_b128 -> bf16x8 (16B-aligned)
__device__ __forceinline__ bf16x8 ld16(const u16* p) {
    const uint4_a* q = (const uint4_a*)__builtin_assume_aligned((const void*)p, 16);
    return __builtin_bit_cast(bf16x8, *q);
}

// ---------------------------------------------------------------------------
// Detect: are the float tensors f32 or bf16?  Reads x[0..63] as u16.
// ---------------------------------------------------------------------------
static __global__ void detect_dtype(const u16* __restrict__ xu, int* __restrict__ flag) {
    int lane = threadIdx.x;            // 64 threads
    u16 u = xu[lane];
    int e = (u >> 7) & 0xFF;
    bool plaus = (u == 0) || (e >= 0x6C && e <= 0x86);
    unsigned long long m = __ballot(plaus);
    if (lane == 0) flag[0] = (__popcll(m) >= 56) ? 0 : 1;   // 0 = bf16, 1 = f32
}

// ---------------------------------------------------------------------------
// Prep kernel 1: gwT[col][c] = gamma[c] * qkv_w[c][col]   (768 x 256, bf16)
//                D2[col] = sum_c gamma[c]*W[c][col]        (f32)
//                D3[col] = sum_c beta[c]*W[c][col] + qkv_b (f32)
// ---------------------------------------------------------------------------
static __global__ __launch_bounds__(256) void prep_qkv(
        const void* __restrict__ qkv_w, const void* __restrict__ qkv_b,
        const void* __restrict__ g, const void* __restrict__ be,
        u16* __restrict__ gwT, float* __restrict__ D2, float* __restrict__ D3,
        const int* __restrict__ flagp)
{
    const int isf32 = flagp[0];
    int col = blockIdx.x;          // 0..767
    int c   = threadIdx.x;         // 0..255
    float gv = gload(g, c, isf32), bv = gload(be, c, isf32);
    float wv = gload(qkv_w, c * 768 + col, isf32);
    gwT[col * 256 + c] = f2b(gv * wv);
    float s2 = gv * wv, s3 = bv * wv;
    #pragma unroll
    for (int off = 32; off; off >>= 1) {
        s2 += __shfl_xor(s2, off);
        s3 += __shfl_xor(s3, off);
    }
    __shared__ float p2[4], p3[4];
    int wvid = threadIdx.x >> 6, ln = threadIdx.x & 63;
    if (ln == 0) { p2[wvid] = s2; p3[wvid] = s3; }
    __syncthreads();
    if (threadIdx.x == 0) {
        D2[col] = p2[0] + p2[1] + p2[2] + p2[3];
        D3[col] = p3[0] + p3[1] + p3[2] + p3[3] + gload(qkv_b, col, isf32);
    }
}

// Prep kernel 2: pwT[n][k] = proj_w[k][n]  (256 x 256, bf16)
//                tablef[i] = table[i] as f32 (3600 entries)
static __global__ __launch_bounds__(256) void prep_proj(
        const void* __restrict__ proj_w, u16* __restrict__ pwT,
        const void* __restrict__ table, float* __restrict__ tablef,
        const int* __restrict__ flagp)
{
    const int isf32 = flagp[0];
    int nrow = blockIdx.x, k = threadIdx.x;
    pwT[nrow * 256 + k] = f2b(gload(proj_w, k * 256 + nrow, isf32));
    int gid = blockIdx.x * 256 + threadIdx.x;
    if (gid < (2 * WSZ - 1) * (2 * WSZ - 1) * NH)
        tablef[gid] = gload(table, gid, isf32);
}

// ---------------------------------------------------------------------------
// Main fused kernel: one workgroup (4 waves) per window.  3 WG/CU.
// ---------------------------------------------------------------------------
static __global__ __launch_bounds__(256, 3) void win_attn(
    const void* __restrict__ x, void* __restrict__ out,
    const u16* __restrict__ gwT, const u16* __restrict__ pwT,
    const float* __restrict__ D2, const float* __restrict__ D3,
    const void* __restrict__ proj_b, const void* __restrict__ postg,
    const void* __restrict__ postb, const float* __restrict__ tablef,
    const int* __restrict__ flagp)
{
    __shared__ __align__(16) u16 sm_t[LTOK * TP];   // 33,024 B  tokens, reused for out
    __shared__ __align__(16) u16 sm_p[LTOK * PP3];  //  8,192 B  probs (unnorm), swizzled
    __shared__ __align__(16) u16 sm_oh[LTOK * OP3]; //  5,120 B  O head-pair [tok][0..31]
    __shared__ __align__(16) u16 sm_q[LTOK * QP3];  //  2,560 B  q-hat [tok][d]
    __shared__ __align__(16) u16 sm_k[LTOK * QP3];  //  2,560 B  k-hat [tok][d]
    __shared__ __align__(16) u16 sm_vt[NH * VP3];   //  2,048 B  v^T [d][tok], swizzled
    __shared__ float sm_mean[LTOK], sm_rstd[LTOK];  //    512 B
    // total ~54 KB -> 3 WG/CU

    const int isf32 = flagp[0];
    const int tid  = threadIdx.x;
    const int wv   = tid >> 6;
    const int lane = tid & 63;
    const int quad = lane >> 4;
    const int n15  = lane & 15;

    // field-swap swizzle: 8 windows sharing an output 128B line -> same XCD,
    // dispatched within 64 slots of each other (write-merge in L2).
    const int b0 = blockIdx.x;
    const int b  = (b0 & ~63) | ((b0 & 7) << 3) | ((b0 >> 3) & 7);
    const int nb = b >> 10, wh = (b >> 5) & 31, wwi = b & 31;
    const int base = nb * (CCH * HWP) + wh * (8 * WW2) + wwi * 8; // + c*HWP + i*WW2 + j

    // ---- Phase 0: load window into sm_t ----
    if (isf32) {
        const float* xf = (const float*)x;
        #pragma unroll
        for (int r = 0; r < 8; ++r) {
            int s = tid + r * 256;
            int c = s >> 3, i = s & 7;
            const float* src = xf + base + c * HWP + i * WW2;
            float4 a = *(const float4_a*)(src);
            float4 d = *(const float4_a*)(src + 4);
            u16* dst = &sm_t[(i * 8) * TP + c];
            dst[0 * TP] = f2b(a.x);  dst[1 * TP] = f2b(a.y);
            dst[2 * TP] = f2b(a.z);  dst[3 * TP] = f2b(a.w);
            dst[4 * TP] = f2b(d.x);  dst[5 * TP] = f2b(d.y);
            dst[6 * TP] = f2b(d.z);  dst[7 * TP] = f2b(d.w);
        }
    } else {
        const u16* xu = (const u16*)x;
        #pragma unroll
        for (int r = 0; r < 8; ++r) {
            int s = tid + r * 256;
            int c = s >> 3, i = s & 7;
            const uint4 v = *(const uint4_a*)(xu + base + c * HWP + i * WW2);
            u16* dst = &sm_t[(i * 8) * TP + c];
            dst[0 * TP] = (u16)(v.x & 0xffff);  dst[1 * TP] = (u16)(v.x >> 16);
            dst[2 * TP] = (u16)(v.y & 0xffff);  dst[3 * TP] = (u16)(v.y >> 16);
            dst[4 * TP] = (u16)(v.z & 0xffff);  dst[5 * TP] = (u16)(v.z >> 16);
            dst[6 * TP] = (u16)(v.w & 0xffff);  dst[7 * TP] = (u16)(v.w >> 16);
        }
    }
    __syncthreads();   // sm_t visible to all waves

    // ---- Phase 0b: pre-LN stats (4 threads per token, same-wave consume) ----
    {
        int l = tid >> 2, g = tid & 3;
        float s = 0.f, ss = 0.f;
        const u16* row = &sm_t[l * TP + g * 64];
        #pragma unroll
        for (int e = 0; e < 64; ++e) {
            float a = b2f(row[e]);
            s += a; ss += a * a;
        }
        s += __shfl_xor(s, 1); ss += __shfl_xor(ss, 1);
        s += __shfl_xor(s, 2); ss += __shfl_xor(ss, 2);
        if (g == 0) {
            float mean = s * (1.f / 256.f);
            float var  = ss * (1.f / 256.f) - mean * mean;
            sm_mean[l] = mean;
            sm_rstd[l] = rsqrtf(var + 1e-5f);
        }
    }

    // per-lane row constants (C/D rows: tok = wv*16 + quad*4 + r)
    float s4[4], ms4[4];
    #pragma unroll
    for (int r = 0; r < 4; ++r) {
        int tok = wv * 16 + quad * 4 + r;
        float mu = sm_mean[tok], sd = sm_rstd[tok];
        s4[r] = sd; ms4[r] = -mu * sd;
    }

    // hoist QKV A-fragments (row = wv*16 + n15) into registers
    bf16x8 afr[8];
    {
        const u16* arow = &sm_t[(wv * 16 + n15) * TP];
        #pragma unroll
        for (int kb = 0; kb < 8; ++kb) {
            #pragma unroll
            for (int j = 0; j < 8; ++j)
                afr[kb][j] = __builtin_bit_cast(__bf16, arow[kb * 32 + quad * 8 + j]);
        }
    }

    // head-invariant rel-bias table offsets (idx*16; +h per head)
    int toff[4][4];
    #pragma unroll
    for (int ct = 0; ct < 4; ++ct) {
        int key = ct * 16 + n15, im = key >> 3, jm = key & 7;
        #pragma unroll
        for (int r = 0; r < 4; ++r) {
            int tok = wv * 16 + quad * 4 + r;
            int il = tok >> 3, jl = tok & 7;
            toff[ct][r] = ((il - im + 7) * 15 + (jl - jm + 7)) * 16;
        }
    }

    f32x4 accp[16];
    #pragma unroll
    for (int t2 = 0; t2 < 16; ++t2) accp[t2] = f32x4{0.f, 0.f, 0.f, 0.f};
    const f32x4 zero4 = f32x4{0.f, 0.f, 0.f, 0.f};

    // A-phase: QKV GEMM + LN-fold + cosine norm for head hh -> registers
    auto compute_A = [&](int hh, float* qv, float* kv, float* vvv) {
        f32x4 aq = zero4, ak = zero4, av = zero4;
        const u16* gq = &gwT[(hh * 16 + n15) * 256 + quad * 8];
        const u16* gk = gq + 256 * 256;
        const u16* gv = gq + 512 * 256;
        #pragma unroll
        for (int kb = 0; kb < 8; ++kb) {
            bf16x8 bq = __builtin_bit_cast(bf16x8, *(const uint4_a*)(gq + kb * 32));
            bf16x8 bk = __builtin_bit_cast(bf16x8, *(const uint4_a*)(gk + kb * 32));
            bf16x8 bv = __builtin_bit_cast(bf16x8, *(const uint4_a*)(gv + kb * 32));
            aq = __builtin_amdgcn_mfma_f32_16x16x32_bf16(afr[kb], bq, aq, 0, 0, 0);
            ak = __builtin_amdgcn_mfma_f32_16x16x32_bf16(afr[kb], bk, ak, 0, 0, 0);
            av = __builtin_amdgcn_mfma_f32_16x16x32_bf16(afr[kb], bv, av, 0, 0, 0);
        }
        float d2q = D2[hh * 16 + n15],       d3q = D3[hh * 16 + n15];
        float d2k = D2[256 + hh * 16 + n15], d3k = D3[256 + hh * 16 + n15];
        float d2v = D2[512 + hh * 16 + n15], d3v = D3[512 + hh * 16 + n15];
        #pragma unroll
        for (int r = 0; r < 4; ++r) {
            qv[r]  = s4[r] * aq[r] + ms4[r] * d2q + d3q;
            kv[r]  = s4[r] * ak[r] + ms4[r] * d2k + d3k;
            vvv[r] = s4[r] * av[r] + ms4[r] * d2v + d3v;
        }
        #pragma unroll
        for (int r = 0; r < 4; ++r) {
            float sq = qv[r] * qv[r], sk = kv[r] * kv[r];
            sq += __shfl_xor(sq, 1); sk += __shfl_xor(sk, 1);
            sq += __shfl_xor(sq, 2); sk += __shfl_xor(sk, 2);
            sq += __shfl_xor(sq, 4); sk += __shfl_xor(sk, 4);
            sq += __shfl_xor(sq, 8); sk += __shfl_xor(sk, 8);
            qv[r] *= rsqrtf(fmaxf(sq, 1e-24f));
            kv[r] *= rsqrtf(fmaxf(sk, 1e-24f));
        }
    };
    // store A results to LDS (q/k pitch 20 scalar; vt XOR-swizzled scalar)
    auto store_A = [&](const float* qv, const float* kv, const float* vvv) {
        #pragma unroll
        for (int r = 0; r < 4; ++r) {
            int tok = wv * 16 + quad * 4 + r;
            sm_q[tok * QP3 + n15] = f2b(qv[r]);
            sm_k[tok * QP3 + n15] = f2b(kv[r]);
            sm_vt[n15 * VP3 + (tok ^ ((n15 & 7) << 3))] = f2b(vvv[r]);
        }
    };

    // ---- prologue: head 0's A-phase + bias prefetch ----
    float qv[4], kv[4], vv[4];
    compute_A(0, qv, kv, vv);
    store_A(qv, kv, vv);
    f32x4 biasv[4];
    #pragma unroll
    for (int ct = 0; ct < 4; ++ct)
        #pragma unroll
        for (int r = 0; r < 4; ++r)
            biasv[ct][r] = tablef[toff[ct][r]];
    __syncthreads();   // q,k,vt(0) visible

    // =================== head loop (2 barriers per head) ===================
    for (int h = 0; h < 16; ++h) {
        // --- B: scores = q-hat @ k-hat^T (bias as acc init), softmax ---
        f32x4 sc[4];
        {
            bf16x8 aqf = {};
            if (quad < 2) aqf = ld_qk(&sm_q[(wv * 16 + n15) * QP3 + quad * 8]);
            #pragma unroll
            for (int ct = 0; ct < 4; ++ct) {
                bf16x8 bkf = {};
                if (quad < 2) bkf = ld_qk(&sm_k[(ct * 16 + n15) * QP3 + quad * 8]);
                sc[ct] = __builtin_amdgcn_mfma_f32_16x16x32_bf16(aqf, bkf, biasv[ct], 0, 0, 0);
            }
        }
        // prefetch bias for next head (overwrites biasv; dead after MFMA above)
        if (h < 15) {
            #pragma unroll
            for (int ct = 0; ct < 4; ++ct)
                #pragma unroll
                for (int r = 0; r < 4; ++r)
                    biasv[ct][r] = tablef[toff[ct][r] + h + 1];
        }
        // softmax: NO max-subtraction (cosine attn bounds |s| <= ~1.1);
        // store unnormalized exp immediately; 1/sum deferred to post-PV.
        float inv[4];
        #pragma unroll
        for (int r = 0; r < 4; ++r) {
            float e0 = __expf(sc[0][r]), e1 = __expf(sc[1][r]);
            float e2 = __expf(sc[2][r]), e3 = __expf(sc[3][r]);
            int tok = wv * 16 + quad * 4 + r;
            int t3 = (tok & 7) << 3;
            sm_p[tok * PP3 + (( 0 + n15) ^ t3)] = f2b(e0);
            sm_p[tok * PP3 + ((16 + n15) ^ t3)] = f2b(e1);
            sm_p[tok * PP3 + ((32 + n15) ^ t3)] = f2b(e2);
            sm_p[tok * PP3 + ((48 + n15) ^ t3)] = f2b(e3);
            float sm = (e0 + e1) + (e2 + e3);
            sm += __shfl_xor(sm, 1); sm += __shfl_xor(sm, 2);
            sm += __shfl_xor(sm, 4); sm += __shfl_xor(sm, 8);
            inv[r] = 1.f / sm;
        }
        // NO barrier: sm_p rows read in C are the same wave's rows.

        // --- C: O_h = (P @ V) * inv ---
        f32x4 ov = zero4;
        {
            int prow = wv * 16 + n15;
            int pxor = (prow & 7) << 3, vxor = (n15 & 7) << 3;
            #pragma unroll
            for (int ks = 0; ks < 2; ++ks) {
                bf16x8 ap  = ld16(&sm_p[prow * PP3 + ((ks * 32 + quad * 8) ^ pxor)]);
                bf16x8 bvf = ld16(&sm_vt[n15 * VP3 + ((ks * 32 + quad * 8) ^ vxor)]);
                ov = __builtin_amdgcn_mfma_f32_16x16x32_bf16(ap, bvf, ov, 0, 0, 0);
            }
        }
        #pragma unroll
        for (int r = 0; r < 4; ++r) {
            int tok = wv * 16 + quad * 4 + r;
            sm_oh[tok * OP3 + (h & 1) * 16 + n15] = f2b(ov[r] * inv[r]);
        }
        // NO barrier: sm_oh rows read in D are the same wave's rows.

        // --- A(h+1): register-resident, overlaps B/C/D of head h ---
        if (h < 15) compute_A(h + 1, qv, kv, vv);

        // --- D: every odd head, accumulate proj for the head pair (K=32) ---
        if (h & 1) {
            int hp = h >> 1;
            bf16x8 aof = ld16(&sm_oh[(wv * 16 + n15) * OP3 + quad * 8]);
            const u16* pwb = &pwT[n15 * 256 + hp * 32 + quad * 8];
            #pragma unroll
            for (int t2 = 0; t2 < 16; ++t2) {
                bf16x8 bpf = __builtin_bit_cast(bf16x8, *(const uint4_a*)(pwb + t2 * 16 * 256));
                accp[t2] = __builtin_amdgcn_mfma_f32_16x16x32_bf16(aof, bpf, accp[t2], 0, 0, 0);
            }
        }

        if (h == 15) break;            // uniform; skip tail barriers
        __syncthreads();               // all waves done reading sm_q/k/vt(h)
        store_A(qv, kv, vv);           // publish head h+1
        __syncthreads();               // visible before B(h+1)
    }

    // =================== epilogue ===================
    {
        // out1 = t + o@proj_w + proj_b   (in place in accp)
        #pragma unroll
        for (int t2 = 0; t2 < 16; ++t2) {
            int col = t2 * 16 + n15;
            float pb = gload(proj_b, col, isf32);
            #pragma unroll
            for (int r = 0; r < 4; ++r) {
                int tok = wv * 16 + quad * 4 + r;
                accp[t2][r] += pb + b2f(sm_t[tok * TP + col]);
            }
        }
        // post-LN row stats over 256 channels
        float sr[4] = {0, 0, 0, 0}, ssr[4] = {0, 0, 0, 0};
        #pragma unroll
        for (int t2 = 0; t2 < 16; ++t2) {
            #pragma unroll
            for (int r = 0; r < 4; ++r) { float v = accp[t2][r]; sr[r] += v; ssr[r] += v * v; }
        }
        #pragma unroll
        for (int r = 0; r < 4; ++r) {
            sr[r] += __shfl_xor(sr[r], 1); ssr[r] += __shfl_xor(ssr[r], 1);
            sr[r] += __shfl_xor(sr[r], 2); ssr[r] += __shfl_xor(ssr[r], 2);
            sr[r] += __shfl_xor(sr[r], 4); ssr[r] += __shfl_xor(ssr[r], 4);
            sr[r] += __shfl_xor(sr[r], 8); ssr[r] += __shfl_xor(ssr[r], 8);
        }
        float mean2[4], rs2[4];
        #pragma unroll
        for (int r = 0; r < 4; ++r) {
            float m = sr[r] * (1.f / 256.f);
            float v = ssr[r] * (1.f / 256.f) - m * m;
            mean2[r] = m; rs2[r] = rsqrtf(v + 1e-5f);
        }
        // NO barrier: each wave reads and rewrites only its own sm_t rows.
        #pragma unroll
        for (int t2 = 0; t2 < 16; ++t2) {
            int col = t2 * 16 + n15;
            float pg = gload(postg, col, isf32), pb2 = gload(postb, col, isf32);
            #pragma unroll
            for (int r = 0; r < 4; ++r) {
                int tok = wv * 16 + quad * 4 + r;
                float o1 = accp[t2][r];
                float fin = o1 + (o1 - mean2[r]) * rs2[r] * pg + pb2;
                sm_t[tok * TP + col] = f2b(fin);
            }
        }
    }
    __syncthreads();   // store phase reads sm_t transposed (cross-wave)

    // ---- store (mirror of load) ----
    if (isf32) {
        float* outf = (float*)out;
        #pragma unroll
        for (int r = 0; r < 8; ++r) {
            int s = tid + r * 256;
            int c = s >> 3, i = s & 7;
            const u16* src = &sm_t[(i * 8) * TP + c];
            float* dst = outf + base + c * HWP + i * WW2;
            float4 a, d;
            a.x = b2f(src[0 * TP]); a.y = b2f(src[1 * TP]);
            a.z = b2f(src[2 * TP]); a.w = b2f(src[3 * TP]);
            d.x = b2f(src[4 * TP]); d.y = b2f(src[5 * TP]);
            d.z = b2f(src[6 * TP]); d.w = b2f(src[7 * TP]);
            *(float4_a*)dst = a;
            *(float4_a*)(dst + 4) = d;
        }
    } else {
        u16* outu = (u16*)out;
        #pragma unroll
        for (int r = 0; r < 8; ++r) {
            int s = tid + r * 256;
            int c = s >> 3, i = s & 7;
            const u16* src = &sm_t[(i * 8) * TP + c];
            uint4 v;
            v.x = (unsigned)src[0 * TP] | ((unsigned)src[1 * TP] << 16);
            v.y = (unsigned)src[2 * TP] | ((unsigned)src[3 * TP] << 16);
            v.z = (unsigned)src[4 * TP] | ((unsigned)src[5 * TP] << 16);
            v.w = (unsigned)src[6 * TP] | ((unsigned)src[7 * TP] << 16);
            *(uint4_a*)(outu + base + c * HWP + i * WW2) = v;
        }
    }
}

// ---------------------------------------------------------------------------
extern "C" void kernel_launch(void* const* d_in, const int* in_sizes, int n_in,
                              void* d_out, int out_size, void* d_ws, size_t ws_size,
                              hipStream_t stream) {
    const void* x     = d_in[0];
    const void* preg  = d_in[1];
    const void* preb  = d_in[2];
    const void* postg = d_in[3];
    const void* postb = d_in[4];
    const void* qkvw  = d_in[5];
    const void* qkvb  = d_in[6];
    const void* projw = d_in[7];
    const void* projb = d_in[8];
    const void* table = d_in[9];

    char* ws = (char*)d_ws;
    u16*   gwT = (u16*)(ws);                  // 768*256*2 = 393216
    u16*   pwT = (u16*)(ws + 393216);         // 256*256*2 = 131072  -> 524288
    float* D2  = (float*)(ws + 524288);       // 768*4 -> 527360
    float* D3  = (float*)(ws + 527360);       // 768*4 -> 530432
    float* tbf = (float*)(ws + 530432);       // 3600*4 = 14400 -> 544832
    int*   flg = (int*)(ws + 544832);         // 4 B

    detect_dtype<<<1, 64, 0, stream>>>((const u16*)x, flg);
    prep_qkv<<<768, 256, 0, stream>>>(qkvw, qkvb, preg, preb, gwT, D2, D3, flg);
    prep_proj<<<256, 256, 0, stream>>>(projw, pwT, table, tbf, flg);
    win_attn<<<NWIN, 256, 0, stream>>>(x, d_out, gwT, pwT, D2, D3,
                                       projb, postg, postb, tbf, flg);
}

// Round 4
// 1064.369 us; speedup vs baseline: 1.2372x; 1.2372x over previous
//
#include <hip/hip_runtime.h>

// ---------------------------------------------------------------------------
// MetNet-3 BlockAttention, fused per-window MFMA kernel for gfx950.
// R7 = R4 (best verified, 922us) + exactly two changes:
//  1. NATURAL block order (no swizzle).  Empirical: R0 natural order gave
//     WRITE=142MB (1.06x output); both swizzles gave 676-849MB.  The 4
//     windows sharing each 128B output line are dispatched adjacently and
//     merge in L2 before eviction.
//  2. SHORT softmax (verified numerically in R6): no max-subtraction
//     (cosine attn bounds |s|<=~1.2), store unnormalized exp immediately,
//     defer 1/sum to post-PV scale.  Removes the fmax tree + max-shuffle
//     chain from the per-head critical path.
// Everything else identical to R4: LDS 53,760B -> 3 WG/CU, 2 barriers/head,
// scalar LDS reads, sm_zero pad trick, bias as MFMA C-init, rsqrtf norm.
// R5/R6's A-phase pipelining + vector LDS reads REVERTED (regressed 26%,
// VALUBusy fell 12->8.4%).
// ---------------------------------------------------------------------------

#define WSZ 8
#define LTOK 64
#define NH 16
#define CCH 256
#define WW2 256
#define HWP 65536          // H*W
#define NWIN 2048          // 2 * 32 * 32 windows

#define TP 258             // sm_t pitch (elements)
#define QP2 18             // sm_q / sm_k pitch (16 data cols, no zero pad)
#define VP2 66             // sm_vt pitch
#define PP2 66             // sm_p pitch
#define OHP 36             // sm_oh pitch

typedef __bf16 bf16x8 __attribute__((ext_vector_type(8)));
typedef float  f32x4  __attribute__((ext_vector_type(4)));
typedef unsigned short u16;
typedef uint4  __attribute__((may_alias)) uint4_a;
typedef float4 __attribute__((may_alias)) float4_a;

__device__ __forceinline__ float b2f(u16 u) {
    return (float)__builtin_bit_cast(__bf16, u);
}
__device__ __forceinline__ u16 f2b(float f) {
    return __builtin_bit_cast(u16, (__bf16)f);
}
__device__ __forceinline__ __bf16 u2b(u16 u) {
    return __builtin_bit_cast(__bf16, u);
}
// dtype-adaptive scalar load of logical element idx
__device__ __forceinline__ float gload(const void* p, int idx, int isf32) {
    return isf32 ? ((const float*)p)[idx] : b2f(((const u16*)p)[idx]);
}

// ---------------------------------------------------------------------------
// Detect: are the float tensors f32 or bf16?  Reads x[0..63] as u16.
// ---------------------------------------------------------------------------
static __global__ void detect_dtype(const u16* __restrict__ xu, int* __restrict__ flag) {
    int lane = threadIdx.x;            // 64 threads
    u16 u = xu[lane];
    int e = (u >> 7) & 0xFF;
    bool plaus = (u == 0) || (e >= 0x6C && e <= 0x86);
    unsigned long long m = __ballot(plaus);
    if (lane == 0) flag[0] = (__popcll(m) >= 56) ? 0 : 1;   // 0 = bf16, 1 = f32
}

// ---------------------------------------------------------------------------
// Prep kernel 1: gwT[col][c] = gamma[c] * qkv_w[c][col]   (768 x 256, bf16)
//                D2[col] = sum_c gamma[c]*W[c][col]        (f32)
//                D3[col] = sum_c beta[c]*W[c][col] + qkv_b (f32)
// ---------------------------------------------------------------------------
static __global__ __launch_bounds__(256) void prep_qkv(
        const void* __restrict__ qkv_w, const void* __restrict__ qkv_b,
        const void* __restrict__ g, const void* __restrict__ be,
        u16* __restrict__ gwT, float* __restrict__ D2, float* __restrict__ D3,
        const int* __restrict__ flagp)
{
    const int isf32 = flagp[0];
    int col = blockIdx.x;          // 0..767
    int c   = threadIdx.x;         // 0..255
    float gv = gload(g, c, isf32), bv = gload(be, c, isf32);
    float wv = gload(qkv_w, c * 768 + col, isf32);
    gwT[col * 256 + c] = f2b(gv * wv);
    float s2 = gv * wv, s3 = bv * wv;
    #pragma unroll
    for (int off = 32; off; off >>= 1) {
        s2 += __shfl_xor(s2, off);
        s3 += __shfl_xor(s3, off);
    }
    __shared__ float p2[4], p3[4];
    int wvid = threadIdx.x >> 6, ln = threadIdx.x & 63;
    if (ln == 0) { p2[wvid] = s2; p3[wvid] = s3; }
    __syncthreads();
    if (threadIdx.x == 0) {
        D2[col] = p2[0] + p2[1] + p2[2] + p2[3];
        D3[col] = p3[0] + p3[1] + p3[2] + p3[3] + gload(qkv_b, col, isf32);
    }
}

// Prep kernel 2: pwT[n][k] = proj_w[k][n]  (256 x 256, bf16)
//                tablef[i] = table[i] as f32 (3600 entries)
static __global__ __launch_bounds__(256) void prep_proj(
        const void* __restrict__ proj_w, u16* __restrict__ pwT,
        const void* __restrict__ table, float* __restrict__ tablef,
        const int* __restrict__ flagp)
{
    const int isf32 = flagp[0];
    int nrow = blockIdx.x, k = threadIdx.x;
    pwT[nrow * 256 + k] = f2b(gload(proj_w, k * 256 + nrow, isf32));
    int gid = blockIdx.x * 256 + threadIdx.x;
    if (gid < (2 * WSZ - 1) * (2 * WSZ - 1) * NH)
        tablef[gid] = gload(table, gid, isf32);
}

// ---------------------------------------------------------------------------
// Main fused kernel: one workgroup (4 waves) per window.  3 WG/CU.
// ---------------------------------------------------------------------------
static __global__ __launch_bounds__(256, 3) void win_attn(
    const void* __restrict__ x, void* __restrict__ out,
    const u16* __restrict__ gwT, const u16* __restrict__ pwT,
    const float* __restrict__ D2, const float* __restrict__ D3,
    const void* __restrict__ proj_b, const void* __restrict__ postg,
    const void* __restrict__ postb, const float* __restrict__ tablef,
    const int* __restrict__ flagp)
{
    __shared__ u16 sm_t[LTOK * TP];      // window tokens t, reused for output
    __shared__ u16 sm_q[LTOK * QP2];     // q-hat  [tok][d] 16 cols
    __shared__ u16 sm_k[LTOK * QP2];     // k-hat  [tok][d]
    __shared__ u16 sm_vt[NH * VP2];      // v^T    [d][tok]
    __shared__ u16 sm_p[LTOK * PP2];     // probs (unnormalized)  [tok][key]
    __shared__ u16 sm_oh[LTOK * OHP];    // O head-pair [tok][0..31]
    __shared__ float sm_mean[LTOK], sm_rstd[LTOK];
    __shared__ u16 sm_zero[16];          // K-pad zeros for quad>=2 fragments

    const int isf32 = flagp[0];
    const int tid  = threadIdx.x;
    const int wv   = tid >> 6;
    const int lane = tid & 63;
    const int quad = lane >> 4;
    const int n15  = lane & 15;

    // NATURAL block order: adjacent blocks = adjacent wwi -> the 4 windows
    // sharing each 128B line are dispatched in adjacent slots (write merge).
    const int b  = blockIdx.x;
    const int nb = b >> 10, wh = (b >> 5) & 31, wwi = b & 31;
    const int base = nb * (CCH * HWP) + wh * (8 * WW2) + wwi * 8; // + c*HWP + i*WW2 + j

    if (tid < 16) sm_zero[tid] = 0;

    // ---- Phase 0: load window into sm_t ----
    if (isf32) {
        const float* xf = (const float*)x;
        #pragma unroll
        for (int r = 0; r < 8; ++r) {
            int s = tid + r * 256;
            int c = s >> 3, i = s & 7;
            const float* src = xf + base + c * HWP + i * WW2;
            float4 a = *(const float4_a*)(src);
            float4 d = *(const float4_a*)(src + 4);
            u16* dst = &sm_t[(i * 8) * TP + c];
            dst[0 * TP] = f2b(a.x);  dst[1 * TP] = f2b(a.y);
            dst[2 * TP] = f2b(a.z);  dst[3 * TP] = f2b(a.w);
            dst[4 * TP] = f2b(d.x);  dst[5 * TP] = f2b(d.y);
            dst[6 * TP] = f2b(d.z);  dst[7 * TP] = f2b(d.w);
        }
    } else {
        const u16* xu = (const u16*)x;
        #pragma unroll
        for (int r = 0; r < 8; ++r) {
            int s = tid + r * 256;
            int c = s >> 3, i = s & 7;
            const uint4 v = *(const uint4_a*)(xu + base + c * HWP + i * WW2);
            u16* dst = &sm_t[(i * 8) * TP + c];
            dst[0 * TP] = (u16)(v.x & 0xffff);  dst[1 * TP] = (u16)(v.x >> 16);
            dst[2 * TP] = (u16)(v.y & 0xffff);  dst[3 * TP] = (u16)(v.y >> 16);
            dst[4 * TP] = (u16)(v.z & 0xffff);  dst[5 * TP] = (u16)(v.z >> 16);
            dst[6 * TP] = (u16)(v.w & 0xffff);  dst[7 * TP] = (u16)(v.w >> 16);
        }
    }
    __syncthreads();   // sm_t + sm_zero visible to all waves

    // ---- Phase 0b: pre-LN stats (4 threads per token, same-wave consume) ----
    {
        int l = tid >> 2, g = tid & 3;
        float s = 0.f, ss = 0.f;
        const u16* row = &sm_t[l * TP + g * 64];
        #pragma unroll
        for (int e = 0; e < 64; ++e) {
            float a = b2f(row[e]);
            s += a; ss += a * a;
        }
        s += __shfl_xor(s, 1); ss += __shfl_xor(ss, 1);
        s += __shfl_xor(s, 2); ss += __shfl_xor(ss, 2);
        if (g == 0) {
            float mean = s * (1.f / 256.f);
            float var  = ss * (1.f / 256.f) - mean * mean;
            sm_mean[l] = mean;
            sm_rstd[l] = rsqrtf(var + 1e-5f);
        }
    }

    // per-lane row constants (C/D rows: tok = wv*16 + quad*4 + r)
    float s4[4], ms4[4];
    #pragma unroll
    for (int r = 0; r < 4; ++r) {
        int tok = wv * 16 + quad * 4 + r;
        float mu = sm_mean[tok], sd = sm_rstd[tok];
        s4[r] = sd; ms4[r] = -mu * sd;
    }

    // hoist QKV A-fragments (row = wv*16 + n15) into registers
    bf16x8 afr[8];
    {
        const u16* arow = &sm_t[(wv * 16 + n15) * TP];
        #pragma unroll
        for (int kb = 0; kb < 8; ++kb) {
            #pragma unroll
            for (int j = 0; j < 8; ++j)
                afr[kb][j] = u2b(arow[kb * 32 + quad * 8 + j]);
        }
    }

    // hoist head-invariant rel-bias table offsets (idx*16; +h per head)
    int toff[4][4];
    #pragma unroll
    for (int ct = 0; ct < 4; ++ct) {
        int key = ct * 16 + n15, im = key >> 3, jm = key & 7;
        #pragma unroll
        for (int r = 0; r < 4; ++r) {
            int tok = wv * 16 + quad * 4 + r;
            int il = tok >> 3, jl = tok & 7;
            toff[ct][r] = ((il - im + 7) * 15 + (jl - jm + 7)) * 16;
        }
    }

    f32x4 accp[16];
    #pragma unroll
    for (int t2 = 0; t2 < 16; ++t2) accp[t2] = f32x4{0.f, 0.f, 0.f, 0.f};
    const f32x4 zero4 = f32x4{0.f, 0.f, 0.f, 0.f};

    // =================== head loop (2 barriers per head) ===================
    for (int h = 0; h < 16; ++h) {
        // --- A: QKV GEMM for this head (wave w: token rows 16w..16w+16) ---
        f32x4 aq = zero4, ak = zero4, av = zero4;
        const u16* gq = &gwT[(h * 16 + n15) * 256 + quad * 8];
        const u16* gk = gq + 256 * 256;
        const u16* gv = gq + 512 * 256;
        #pragma unroll
        for (int kb = 0; kb < 8; ++kb) {
            bf16x8 bq = __builtin_bit_cast(bf16x8, *(const uint4_a*)(gq + kb * 32));
            bf16x8 bk = __builtin_bit_cast(bf16x8, *(const uint4_a*)(gk + kb * 32));
            bf16x8 bv = __builtin_bit_cast(bf16x8, *(const uint4_a*)(gv + kb * 32));
            aq = __builtin_amdgcn_mfma_f32_16x16x32_bf16(afr[kb], bq, aq, 0, 0, 0);
            ak = __builtin_amdgcn_mfma_f32_16x16x32_bf16(afr[kb], bk, ak, 0, 0, 0);
            av = __builtin_amdgcn_mfma_f32_16x16x32_bf16(afr[kb], bv, av, 0, 0, 0);
        }
        // affine LN-fold epilogue: val = rstd*D1 - mu*rstd*D2 + D3
        float d2q = D2[h * 16 + n15],       d3q = D3[h * 16 + n15];
        float d2k = D2[256 + h * 16 + n15], d3k = D3[256 + h * 16 + n15];
        float d2v = D2[512 + h * 16 + n15], d3v = D3[512 + h * 16 + n15];
        float qv[4], kv[4], vv[4];
        #pragma unroll
        for (int r = 0; r < 4; ++r) {
            qv[r] = s4[r] * aq[r] + ms4[r] * d2q + d3q;
            kv[r] = s4[r] * ak[r] + ms4[r] * d2k + d3k;
            vv[r] = s4[r] * av[r] + ms4[r] * d2v + d3v;
        }
        // cosine normalize q,k per token (reduce over d = lane&15 group)
        #pragma unroll
        for (int r = 0; r < 4; ++r) {
            float sq = qv[r] * qv[r], sk = kv[r] * kv[r];
            sq += __shfl_xor(sq, 1); sk += __shfl_xor(sk, 1);
            sq += __shfl_xor(sq, 2); sk += __shfl_xor(sk, 2);
            sq += __shfl_xor(sq, 4); sk += __shfl_xor(sk, 4);
            sq += __shfl_xor(sq, 8); sk += __shfl_xor(sk, 8);
            qv[r] *= rsqrtf(fmaxf(sq, 1e-24f));
            kv[r] *= rsqrtf(fmaxf(sk, 1e-24f));
        }
        #pragma unroll
        for (int r = 0; r < 4; ++r) {
            int tok = wv * 16 + quad * 4 + r;
            sm_q[tok * QP2 + n15] = f2b(qv[r]);
            sm_k[tok * QP2 + n15] = f2b(kv[r]);
            sm_vt[n15 * VP2 + tok] = f2b(vv[r]);   // v^T, scalar write
        }
        __syncthreads();   // k, vt cross-wave visibility (q is wave-private)

        // --- B: scores = q-hat @ k-hat^T (bias as acc init), short softmax ---
        f32x4 sc[4];
        {
            bf16x8 aqf;
            const u16* qrow = (quad < 2) ? &sm_q[(wv * 16 + n15) * QP2 + quad * 8]
                                         : sm_zero;
            #pragma unroll
            for (int j = 0; j < 8; ++j) aqf[j] = u2b(qrow[j]);
            #pragma unroll
            for (int ct = 0; ct < 4; ++ct) {
                bf16x8 bkf;
                const u16* krow = (quad < 2) ? &sm_k[(ct * 16 + n15) * QP2 + quad * 8]
                                             : sm_zero;
                #pragma unroll
                for (int j = 0; j < 8; ++j) bkf[j] = u2b(krow[j]);
                f32x4 bias;
                #pragma unroll
                for (int r = 0; r < 4; ++r) bias[r] = tablef[toff[ct][r] + h];
                sc[ct] = __builtin_amdgcn_mfma_f32_16x16x32_bf16(aqf, bkf, bias, 0, 0, 0);
            }
        }
        // short softmax: no max-subtraction (cosine attn: |s| <= ~1.2, so
        // exp(s) in [0.3, 3.3] -- safe).  Store unnormalized exp immediately;
        // defer 1/sum to post-PV scale (sum shuffle chain off critical path).
        float inv[4];
        #pragma unroll
        for (int r = 0; r < 4; ++r) {
            float e0 = __expf(sc[0][r]), e1 = __expf(sc[1][r]);
            float e2 = __expf(sc[2][r]), e3 = __expf(sc[3][r]);
            int tok = wv * 16 + quad * 4 + r;
            sm_p[tok * PP2 +  0 + n15] = f2b(e0);
            sm_p[tok * PP2 + 16 + n15] = f2b(e1);
            sm_p[tok * PP2 + 32 + n15] = f2b(e2);
            sm_p[tok * PP2 + 48 + n15] = f2b(e3);
            float sm = (e0 + e1) + (e2 + e3);
            sm += __shfl_xor(sm, 1); sm += __shfl_xor(sm, 2);
            sm += __shfl_xor(sm, 4); sm += __shfl_xor(sm, 8);
            inv[r] = 1.f / sm;
        }
        // NO barrier: sm_p rows read in C are the same wave's rows.

        // --- C: O_h = (P @ V) * inv ---
        f32x4 ov = zero4;
        #pragma unroll
        for (int ks = 0; ks < 2; ++ks) {
            bf16x8 ap, bvf;
            const u16* prow = &sm_p[(wv * 16 + n15) * PP2 + ks * 32 + quad * 8];
            const u16* vrow = &sm_vt[n15 * VP2 + ks * 32 + quad * 8];
            #pragma unroll
            for (int j = 0; j < 8; ++j) { ap[j] = u2b(prow[j]); bvf[j] = u2b(vrow[j]); }
            ov = __builtin_amdgcn_mfma_f32_16x16x32_bf16(ap, bvf, ov, 0, 0, 0);
        }
        #pragma unroll
        for (int r = 0; r < 4; ++r) {
            int tok = wv * 16 + quad * 4 + r;
            sm_oh[tok * OHP + (h & 1) * 16 + n15] = f2b(ov[r] * inv[r]);
        }
        // NO barrier: sm_oh rows read in D are the same wave's rows.

        // --- D: every odd head, accumulate proj for the head pair (K=32) ---
        if (h & 1) {
            int hp = h >> 1;
            bf16x8 aof;
            const u16* orow = &sm_oh[(wv * 16 + n15) * OHP + quad * 8];
            #pragma unroll
            for (int j = 0; j < 8; ++j) aof[j] = u2b(orow[j]);
            const u16* pwb = &pwT[n15 * 256 + hp * 32 + quad * 8];
            #pragma unroll
            for (int t2 = 0; t2 < 16; ++t2) {
                bf16x8 bpf = __builtin_bit_cast(bf16x8, *(const uint4_a*)(pwb + t2 * 16 * 256));
                accp[t2] = __builtin_amdgcn_mfma_f32_16x16x32_bf16(aof, bpf, accp[t2], 0, 0, 0);
            }
        }
        __syncthreads();   // protect sm_q/k/vt rewrite next head
    }

    // =================== epilogue ===================
    {
        // out1 = t + o@proj_w + proj_b   (in place in accp)
        #pragma unroll
        for (int t2 = 0; t2 < 16; ++t2) {
            int col = t2 * 16 + n15;
            float pb = gload(proj_b, col, isf32);
            #pragma unroll
            for (int r = 0; r < 4; ++r) {
                int tok = wv * 16 + quad * 4 + r;
                accp[t2][r] += pb + b2f(sm_t[tok * TP + col]);
            }
        }
        // post-LN row stats over 256 channels
        float sr[4] = {0, 0, 0, 0}, ssr[4] = {0, 0, 0, 0};
        #pragma unroll
        for (int t2 = 0; t2 < 16; ++t2) {
            #pragma unroll
            for (int r = 0; r < 4; ++r) { float v = accp[t2][r]; sr[r] += v; ssr[r] += v * v; }
        }
        #pragma unroll
        for (int r = 0; r < 4; ++r) {
            sr[r] += __shfl_xor(sr[r], 1); ssr[r] += __shfl_xor(ssr[r], 1);
            sr[r] += __shfl_xor(sr[r], 2); ssr[r] += __shfl_xor(ssr[r], 2);
            sr[r] += __shfl_xor(sr[r], 4); ssr[r] += __shfl_xor(ssr[r], 4);
            sr[r] += __shfl_xor(sr[r], 8); ssr[r] += __shfl_xor(ssr[r], 8);
        }
        float mean2[4], rs2[4];
        #pragma unroll
        for (int r = 0; r < 4; ++r) {
            float m = sr[r] * (1.f / 256.f);
            float v = ssr[r] * (1.f / 256.f) - m * m;
            mean2[r] = m; rs2[r] = rsqrtf(v + 1e-5f);
        }
        // NO barrier: each wave reads and rewrites only its own sm_t rows.
        #pragma unroll
        for (int t2 = 0; t2 < 16; ++t2) {
            int col = t2 * 16 + n15;
            float pg = gload(postg, col, isf32), pb2 = gload(postb, col, isf32);
            #pragma unroll
            for (int r = 0; r < 4; ++r) {
                int tok = wv * 16 + quad * 4 + r;
                float o1 = accp[t2][r];
                float fin = o1 + (o1 - mean2[r]) * rs2[r] * pg + pb2;
                sm_t[tok * TP + col] = f2b(fin);
            }
        }
    }
    __syncthreads();   // store phase reads sm_t transposed (cross-wave)

    // ---- store (mirror of load) ----
    if (isf32) {
        float* outf = (float*)out;
        #pragma unroll
        for (int r = 0; r < 8; ++r) {
            int s = tid + r * 256;
            int c = s >> 3, i = s & 7;
            const u16* src = &sm_t[(i * 8) * TP + c];
            float* dst = outf + base + c * HWP + i * WW2;
            float4 a, d;
            a.x = b2f(src[0 * TP]); a.y = b2f(src[1 * TP]);
            a.z = b2f(src[2 * TP]); a.w = b2f(src[3 * TP]);
            d.x = b2f(src[4 * TP]); d.y = b2f(src[5 * TP]);
            d.z = b2f(src[6 * TP]); d.w = b2f(src[7 * TP]);
            *(float4_a*)dst = a;
            *(float4_a*)(dst + 4) = d;
        }
    } else {
        u16* outu = (u16*)out;
        #pragma unroll
        for (int r = 0; r < 8; ++r) {
            int s = tid + r * 256;
            int c = s >> 3, i = s & 7;
            const u16* src = &sm_t[(i * 8) * TP + c];
            uint4 v;
            v.x = (unsigned)src[0 * TP] | ((unsigned)src[1 * TP] << 16);
            v.y = (unsigned)src[2 * TP] | ((unsigned)src[3 * TP] << 16);
            v.z = (unsigned)src[4 * TP] | ((unsigned)src[5 * TP] << 16);
            v.w = (unsigned)src[6 * TP] | ((unsigned)src[7 * TP] << 16);
            *(uint4_a*)(outu + base + c * HWP + i * WW2) = v;
        }
    }
}

// ---------------------------------------------------------------------------
extern "C" void kernel_launch(void* const* d_in, const int* in_sizes, int n_in,
                              void* d_out, int out_size, void* d_ws, size_t ws_size,
                              hipStream_t stream) {
    const void* x     = d_in[0];
    const void* preg  = d_in[1];
    const void* preb  = d_in[2];
    const void* postg = d_in[3];
    const void* postb = d_in[4];
    const void* qkvw  = d_in[5];
    const void* qkvb  = d_in[6];
    const void* projw = d_in[7];
    const void* projb = d_in[8];
    const void* table = d_in[9];

    char* ws = (char*)d_ws;
    u16*   gwT = (u16*)(ws);                  // 768*256*2 = 393216
    u16*   pwT = (u16*)(ws + 393216);         // 256*256*2 = 131072  -> 524288
    float* D2  = (float*)(ws + 524288);       // 768*4 -> 527360
    float* D3  = (float*)(ws + 527360);       // 768*4 -> 530432
    float* tbf = (float*)(ws + 530432);       // 3600*4 = 14400 -> 544832
    int*   flg = (int*)(ws + 544832);         // 4 B

    detect_dtype<<<1, 64, 0, stream>>>((const u16*)x, flg);
    prep_qkv<<<768, 256, 0, stream>>>(qkvw, qkvb, preg, preb, gwT, D2, D3, flg);
    prep_proj<<<256, 256, 0, stream>>>(projw, pwT, table, tbf, flg);
    win_attn<<<NWIN, 256, 0, stream>>>(x, d_out, gwT, pwT, D2, D3,
                                       projb, postg, postb, tbf, flg);
}

// Round 5
// 976.284 us; speedup vs baseline: 1.3488x; 1.0902x over previous
//
#include <hip/hip_runtime.h>

// ---------------------------------------------------------------------------
// MetNet-3 BlockAttention, fused per-window MFMA kernel for gfx950.
// R8: HEAD-QUAD RESTRUCTURE (amortize global-load latency).
// Evidence: per-head wall time ~42K cyc vs ~3K static chain estimate; FETCH
// has ~250MB of gwT/pwT refetch; VGPR=84 means A/D loads issue in shallow
// batches, each paying L2/HBM latency, restarted 16x per block.
//  - Outer loop = 4 head-quads.  A-sweep computes QKV for 4 heads: 96
//    independent dwordx4 loads feed 12 independent 8-deep MFMA chains ->
//    deep memory pipelining instead of 16 shallow restarts.
//  - Inner 4-head loop has ZERO barriers (k/vt written once pre-barrier;
//    sm_p/sm_oh rows are wave-private).  Barriers: 32 -> 8 (+2 fixed).
//  - 8 cosine-norm shuffle chains per quad interleave (latency amortized).
//  - Softmax row-sum via MFMA with a ones-fragment (reuses the P fragment
//    already loaded for PV; off the VALU critical path).  Short softmax
//    retained (no max-sub; verified R6/R7).
//  - LDS 73,504 B -> 2 WG/CU (8 waves/CU ~= the 2.35-block average actually
//    achieved at "3 WG/CU").  __launch_bounds__(256,2), VGPR budget 256.
//  - Natural block order (swizzles hurt: R4/R6 evidence).
// ---------------------------------------------------------------------------

#define WSZ 8
#define LTOK 64
#define NH 16
#define CCH 256
#define WW2 256
#define HWP 65536          // H*W
#define NWIN 2048          // 2 * 32 * 32 windows

#define TP 258             // sm_t pitch (elements)
#define QP2 18             // sm_q / sm_k pitch (16 data cols, no zero pad)
#define VP2 66             // sm_vt pitch
#define PP2 66             // sm_p pitch
#define OHP 36             // sm_oh pitch

typedef __bf16 bf16x8 __attribute__((ext_vector_type(8)));
typedef float  f32x4  __attribute__((ext_vector_type(4)));
typedef unsigned short u16;
typedef uint4  __attribute__((may_alias)) uint4_a;
typedef float4 __attribute__((may_alias)) float4_a;

__device__ __forceinline__ float b2f(u16 u) {
    return (float)__builtin_bit_cast(__bf16, u);
}
__device__ __forceinline__ u16 f2b(float f) {
    return __builtin_bit_cast(u16, (__bf16)f);
}
__device__ __forceinline__ __bf16 u2b(u16 u) {
    return __builtin_bit_cast(__bf16, u);
}
// dtype-adaptive scalar load of logical element idx
__device__ __forceinline__ float gload(const void* p, int idx, int isf32) {
    return isf32 ? ((const float*)p)[idx] : b2f(((const u16*)p)[idx]);
}

// ---------------------------------------------------------------------------
// Detect: are the float tensors f32 or bf16?  Reads x[0..63] as u16.
// ---------------------------------------------------------------------------
static __global__ void detect_dtype(const u16* __restrict__ xu, int* __restrict__ flag) {
    int lane = threadIdx.x;            // 64 threads
    u16 u = xu[lane];
    int e = (u >> 7) & 0xFF;
    bool plaus = (u == 0) || (e >= 0x6C && e <= 0x86);
    unsigned long long m = __ballot(plaus);
    if (lane == 0) flag[0] = (__popcll(m) >= 56) ? 0 : 1;   // 0 = bf16, 1 = f32
}

// ---------------------------------------------------------------------------
// Prep kernel 1: gwT[col][c] = gamma[c] * qkv_w[c][col]   (768 x 256, bf16)
//                D2[col] = sum_c gamma[c]*W[c][col]        (f32)
//                D3[col] = sum_c beta[c]*W[c][col] + qkv_b (f32)
// ---------------------------------------------------------------------------
static __global__ __launch_bounds__(256) void prep_qkv(
        const void* __restrict__ qkv_w, const void* __restrict__ qkv_b,
        const void* __restrict__ g, const void* __restrict__ be,
        u16* __restrict__ gwT, float* __restrict__ D2, float* __restrict__ D3,
        const int* __restrict__ flagp)
{
    const int isf32 = flagp[0];
    int col = blockIdx.x;          // 0..767
    int c   = threadIdx.x;         // 0..255
    float gv = gload(g, c, isf32), bv = gload(be, c, isf32);
    float wv = gload(qkv_w, c * 768 + col, isf32);
    gwT[col * 256 + c] = f2b(gv * wv);
    float s2 = gv * wv, s3 = bv * wv;
    #pragma unroll
    for (int off = 32; off; off >>= 1) {
        s2 += __shfl_xor(s2, off);
        s3 += __shfl_xor(s3, off);
    }
    __shared__ float p2[4], p3[4];
    int wvid = threadIdx.x >> 6, ln = threadIdx.x & 63;
    if (ln == 0) { p2[wvid] = s2; p3[wvid] = s3; }
    __syncthreads();
    if (threadIdx.x == 0) {
        D2[col] = p2[0] + p2[1] + p2[2] + p2[3];
        D3[col] = p3[0] + p3[1] + p3[2] + p3[3] + gload(qkv_b, col, isf32);
    }
}

// Prep kernel 2: pwT[n][k] = proj_w[k][n]  (256 x 256, bf16)
//                tablef[i] = table[i] as f32 (3600 entries)
static __global__ __launch_bounds__(256) void prep_proj(
        const void* __restrict__ proj_w, u16* __restrict__ pwT,
        const void* __restrict__ table, float* __restrict__ tablef,
        const int* __restrict__ flagp)
{
    const int isf32 = flagp[0];
    int nrow = blockIdx.x, k = threadIdx.x;
    pwT[nrow * 256 + k] = f2b(gload(proj_w, k * 256 + nrow, isf32));
    int gid = blockIdx.x * 256 + threadIdx.x;
    if (gid < (2 * WSZ - 1) * (2 * WSZ - 1) * NH)
        tablef[gid] = gload(table, gid, isf32);
}

// ---------------------------------------------------------------------------
// Main fused kernel: one workgroup (4 waves) per window.  2 WG/CU.
// ---------------------------------------------------------------------------
static __global__ __launch_bounds__(256, 2) void win_attn(
    const void* __restrict__ x, void* __restrict__ out,
    const u16* __restrict__ gwT, const u16* __restrict__ pwT,
    const float* __restrict__ D2, const float* __restrict__ D3,
    const void* __restrict__ proj_b, const void* __restrict__ postg,
    const void* __restrict__ postb, const float* __restrict__ tablef,
    const int* __restrict__ flagp)
{
    __shared__ u16 sm_t[LTOK * TP];        // 33,024 B  tokens, reused for out
    __shared__ u16 sm_q[4][LTOK * QP2];    //  9,216 B  q-hat, 4 heads
    __shared__ u16 sm_k[4][LTOK * QP2];    //  9,216 B  k-hat, 4 heads
    __shared__ u16 sm_vt[4][NH * VP2];     //  8,448 B  v^T,   4 heads
    __shared__ u16 sm_p[LTOK * PP2];       //  8,448 B  probs (unnorm), 1 head
    __shared__ u16 sm_oh[LTOK * OHP];      //  4,608 B  O head-pair [tok][0..31]
    __shared__ float sm_mean[LTOK], sm_rstd[LTOK];   // 512 B
    __shared__ u16 sm_zero[16];            // K-pad zeros for quad>=2 fragments
    // total 73,504 B -> 2 WG/CU

    const int isf32 = flagp[0];
    const int tid  = threadIdx.x;
    const int wv   = tid >> 6;
    const int lane = tid & 63;
    const int quad = lane >> 4;
    const int n15  = lane & 15;

    // natural block order (swizzles hurt: R4/R6 evidence)
    const int b  = blockIdx.x;
    const int nb = b >> 10, wh = (b >> 5) & 31, wwi = b & 31;
    const int base = nb * (CCH * HWP) + wh * (8 * WW2) + wwi * 8; // + c*HWP + i*WW2 + j

    if (tid < 16) sm_zero[tid] = 0;

    // ---- Phase 0: load window into sm_t ----
    if (isf32) {
        const float* xf = (const float*)x;
        #pragma unroll
        for (int r = 0; r < 8; ++r) {
            int s = tid + r * 256;
            int c = s >> 3, i = s & 7;
            const float* src = xf + base + c * HWP + i * WW2;
            float4 a = *(const float4_a*)(src);
            float4 d = *(const float4_a*)(src + 4);
            u16* dst = &sm_t[(i * 8) * TP + c];
            dst[0 * TP] = f2b(a.x);  dst[1 * TP] = f2b(a.y);
            dst[2 * TP] = f2b(a.z);  dst[3 * TP] = f2b(a.w);
            dst[4 * TP] = f2b(d.x);  dst[5 * TP] = f2b(d.y);
            dst[6 * TP] = f2b(d.z);  dst[7 * TP] = f2b(d.w);
        }
    } else {
        const u16* xu = (const u16*)x;
        #pragma unroll
        for (int r = 0; r < 8; ++r) {
            int s = tid + r * 256;
            int c = s >> 3, i = s & 7;
            const uint4 v = *(const uint4_a*)(xu + base + c * HWP + i * WW2);
            u16* dst = &sm_t[(i * 8) * TP + c];
            dst[0 * TP] = (u16)(v.x & 0xffff);  dst[1 * TP] = (u16)(v.x >> 16);
            dst[2 * TP] = (u16)(v.y & 0xffff);  dst[3 * TP] = (u16)(v.y >> 16);
            dst[4 * TP] = (u16)(v.z & 0xffff);  dst[5 * TP] = (u16)(v.z >> 16);
            dst[6 * TP] = (u16)(v.w & 0xffff);  dst[7 * TP] = (u16)(v.w >> 16);
        }
    }
    __syncthreads();   // sm_t + sm_zero visible to all waves

    // ---- Phase 0b: pre-LN stats (4 threads per token, same-wave consume) ----
    {
        int l = tid >> 2, g = tid & 3;
        float s = 0.f, ss = 0.f;
        const u16* row = &sm_t[l * TP + g * 64];
        #pragma unroll
        for (int e = 0; e < 64; ++e) {
            float a = b2f(row[e]);
            s += a; ss += a * a;
        }
        s += __shfl_xor(s, 1); ss += __shfl_xor(ss, 1);
        s += __shfl_xor(s, 2); ss += __shfl_xor(ss, 2);
        if (g == 0) {
            float mean = s * (1.f / 256.f);
            float var  = ss * (1.f / 256.f) - mean * mean;
            sm_mean[l] = mean;
            sm_rstd[l] = rsqrtf(var + 1e-5f);
        }
    }

    // per-lane row constants (C/D rows: tok = wv*16 + quad*4 + r)
    float s4[4], ms4[4];
    #pragma unroll
    for (int r = 0; r < 4; ++r) {
        int tok = wv * 16 + quad * 4 + r;
        float mu = sm_mean[tok], sd = sm_rstd[tok];
        s4[r] = sd; ms4[r] = -mu * sd;
    }

    // hoist QKV A-fragments (row = wv*16 + n15) into registers
    bf16x8 afr[8];
    {
        const u16* arow = &sm_t[(wv * 16 + n15) * TP];
        #pragma unroll
        for (int kb = 0; kb < 8; ++kb) {
            #pragma unroll
            for (int j = 0; j < 8; ++j)
                afr[kb][j] = u2b(arow[kb * 32 + quad * 8 + j]);
        }
    }

    // hoist head-invariant rel-bias table offsets (idx*16; +h per head)
    int toff[4][4];
    #pragma unroll
    for (int ct = 0; ct < 4; ++ct) {
        int key = ct * 16 + n15, im = key >> 3, jm = key & 7;
        #pragma unroll
        for (int r = 0; r < 4; ++r) {
            int tok = wv * 16 + quad * 4 + r;
            int il = tok >> 3, jl = tok & 7;
            toff[ct][r] = ((il - im + 7) * 15 + (jl - jm + 7)) * 16;
        }
    }

    f32x4 accp[16];
    #pragma unroll
    for (int t2 = 0; t2 < 16; ++t2) accp[t2] = f32x4{0.f, 0.f, 0.f, 0.f};
    const f32x4 zero4 = f32x4{0.f, 0.f, 0.f, 0.f};

    bf16x8 onesf;
    #pragma unroll
    for (int j = 0; j < 8; ++j) onesf[j] = (__bf16)1.0f;

    // ================= outer loop: 4 head-quads =================
    for (int hq = 0; hq < 4; ++hq) {
        const int H = hq * 4;

        // --- A-sweep: QKV GEMM for 4 heads, 96 independent loads,
        //     12 independent 8-deep MFMA chains (deep memory pipelining) ---
        f32x4 aq[4], ak[4], av[4];
        #pragma unroll
        for (int hh = 0; hh < 4; ++hh) { aq[hh] = zero4; ak[hh] = zero4; av[hh] = zero4; }
        const u16* g0 = &gwT[(H * 16 + n15) * 256 + quad * 8];
        #pragma unroll
        for (int kb = 0; kb < 8; ++kb) {
            #pragma unroll
            for (int hh = 0; hh < 4; ++hh) {
                const u16* gq = g0 + hh * 4096 + kb * 32;
                bf16x8 bq = __builtin_bit_cast(bf16x8, *(const uint4_a*)(gq));
                bf16x8 bk = __builtin_bit_cast(bf16x8, *(const uint4_a*)(gq + 65536));
                bf16x8 bv = __builtin_bit_cast(bf16x8, *(const uint4_a*)(gq + 131072));
                aq[hh] = __builtin_amdgcn_mfma_f32_16x16x32_bf16(afr[kb], bq, aq[hh], 0, 0, 0);
                ak[hh] = __builtin_amdgcn_mfma_f32_16x16x32_bf16(afr[kb], bk, ak[hh], 0, 0, 0);
                av[hh] = __builtin_amdgcn_mfma_f32_16x16x32_bf16(afr[kb], bv, av[hh], 0, 0, 0);
            }
        }
        // LN-fold + cosine norm + LDS store, 4 heads (8 shuffle chains interleave)
        #pragma unroll
        for (int hh = 0; hh < 4; ++hh) {
            int ci = (H + hh) * 16 + n15;
            float d2q = D2[ci],       d3q = D3[ci];
            float d2k = D2[256 + ci], d3k = D3[256 + ci];
            float d2v = D2[512 + ci], d3v = D3[512 + ci];
            float qv[4], kv[4], vv[4];
            #pragma unroll
            for (int r = 0; r < 4; ++r) {
                qv[r] = s4[r] * aq[hh][r] + ms4[r] * d2q + d3q;
                kv[r] = s4[r] * ak[hh][r] + ms4[r] * d2k + d3k;
                vv[r] = s4[r] * av[hh][r] + ms4[r] * d2v + d3v;
            }
            #pragma unroll
            for (int r = 0; r < 4; ++r) {
                float sq = qv[r] * qv[r], sk = kv[r] * kv[r];
                sq += __shfl_xor(sq, 1); sk += __shfl_xor(sk, 1);
                sq += __shfl_xor(sq, 2); sk += __shfl_xor(sk, 2);
                sq += __shfl_xor(sq, 4); sk += __shfl_xor(sk, 4);
                sq += __shfl_xor(sq, 8); sk += __shfl_xor(sk, 8);
                qv[r] *= rsqrtf(fmaxf(sq, 1e-24f));
                kv[r] *= rsqrtf(fmaxf(sk, 1e-24f));
            }
            #pragma unroll
            for (int r = 0; r < 4; ++r) {
                int tok = wv * 16 + quad * 4 + r;
                sm_q[hh][tok * QP2 + n15] = f2b(qv[r]);
                sm_k[hh][tok * QP2 + n15] = f2b(kv[r]);
                sm_vt[hh][n15 * VP2 + tok] = f2b(vv[r]);
            }
        }
        __syncthreads();   // 4 heads of k, vt visible to all waves

        // --- inner loop: 4 heads, ZERO barriers ---
        #pragma unroll
        for (int hh = 0; hh < 4; ++hh) {
            const int h = H + hh;
            // B: scores = q-hat @ k-hat^T (bias as acc init)
            f32x4 sc[4];
            {
                bf16x8 aqf;
                const u16* qrow = (quad < 2) ? &sm_q[hh][(wv * 16 + n15) * QP2 + quad * 8]
                                             : sm_zero;
                #pragma unroll
                for (int j = 0; j < 8; ++j) aqf[j] = u2b(qrow[j]);
                #pragma unroll
                for (int ct = 0; ct < 4; ++ct) {
                    bf16x8 bkf;
                    const u16* krow = (quad < 2) ? &sm_k[hh][(ct * 16 + n15) * QP2 + quad * 8]
                                                 : sm_zero;
                    #pragma unroll
                    for (int j = 0; j < 8; ++j) bkf[j] = u2b(krow[j]);
                    f32x4 bias;
                    #pragma unroll
                    for (int r = 0; r < 4; ++r) bias[r] = tablef[toff[ct][r] + h];
                    sc[ct] = __builtin_amdgcn_mfma_f32_16x16x32_bf16(aqf, bkf, bias, 0, 0, 0);
                }
            }
            // short softmax: store unnormalized exp; no reduction here at all
            #pragma unroll
            for (int r = 0; r < 4; ++r) {
                float e0 = __expf(sc[0][r]), e1 = __expf(sc[1][r]);
                float e2 = __expf(sc[2][r]), e3 = __expf(sc[3][r]);
                int tok = wv * 16 + quad * 4 + r;
                sm_p[tok * PP2 +  0 + n15] = f2b(e0);
                sm_p[tok * PP2 + 16 + n15] = f2b(e1);
                sm_p[tok * PP2 + 32 + n15] = f2b(e2);
                sm_p[tok * PP2 + 48 + n15] = f2b(e3);
            }
            // (no barrier: sm_p rows read below are this wave's rows)

            // C: O_h = P @ V; row-sum of P via MFMA with ones-fragment
            f32x4 ov = zero4, rs = zero4;
            #pragma unroll
            for (int ks = 0; ks < 2; ++ks) {
                bf16x8 ap, bvf;
                const u16* prow = &sm_p[(wv * 16 + n15) * PP2 + ks * 32 + quad * 8];
                const u16* vrow = &sm_vt[hh][n15 * VP2 + ks * 32 + quad * 8];
                #pragma unroll
                for (int j = 0; j < 8; ++j) { ap[j] = u2b(prow[j]); bvf[j] = u2b(vrow[j]); }
                ov = __builtin_amdgcn_mfma_f32_16x16x32_bf16(ap, bvf, ov, 0, 0, 0);
                rs = __builtin_amdgcn_mfma_f32_16x16x32_bf16(ap, onesf, rs, 0, 0, 0);
            }
            #pragma unroll
            for (int r = 0; r < 4; ++r) {
                int tok = wv * 16 + quad * 4 + r;
                sm_oh[tok * OHP + (h & 1) * 16 + n15] = f2b(ov[r] / rs[r]);
            }
            // (no barrier: sm_oh rows read below are this wave's rows)

            // D: every odd head, accumulate proj for the head pair (K=32)
            if (hh & 1) {
                int hp = h >> 1;
                bf16x8 aof;
                const u16* orow = &sm_oh[(wv * 16 + n15) * OHP + quad * 8];
                #pragma unroll
                for (int j = 0; j < 8; ++j) aof[j] = u2b(orow[j]);
                const u16* pwb = &pwT[n15 * 256 + hp * 32 + quad * 8];
                #pragma unroll
                for (int t2 = 0; t2 < 16; ++t2) {
                    bf16x8 bpf = __builtin_bit_cast(bf16x8, *(const uint4_a*)(pwb + t2 * 16 * 256));
                    accp[t2] = __builtin_amdgcn_mfma_f32_16x16x32_bf16(aof, bpf, accp[t2], 0, 0, 0);
                }
            }
        }
        __syncthreads();   // all waves done reading q/k/vt before next A-sweep
    }

    // =================== epilogue ===================
    {
        // out1 = t + o@proj_w + proj_b   (in place in accp)
        #pragma unroll
        for (int t2 = 0; t2 < 16; ++t2) {
            int col = t2 * 16 + n15;
            float pb = gload(proj_b, col, isf32);
            #pragma unroll
            for (int r = 0; r < 4; ++r) {
                int tok = wv * 16 + quad * 4 + r;
                accp[t2][r] += pb + b2f(sm_t[tok * TP + col]);
            }
        }
        // post-LN row stats over 256 channels
        float sr[4] = {0, 0, 0, 0}, ssr[4] = {0, 0, 0, 0};
        #pragma unroll
        for (int t2 = 0; t2 < 16; ++t2) {
            #pragma unroll
            for (int r = 0; r < 4; ++r) { float v = accp[t2][r]; sr[r] += v; ssr[r] += v * v; }
        }
        #pragma unroll
        for (int r = 0; r < 4; ++r) {
            sr[r] += __shfl_xor(sr[r], 1); ssr[r] += __shfl_xor(ssr[r], 1);
            sr[r] += __shfl_xor(sr[r], 2); ssr[r] += __shfl_xor(ssr[r], 2);
            sr[r] += __shfl_xor(sr[r], 4); ssr[r] += __shfl_xor(ssr[r], 4);
            sr[r] += __shfl_xor(sr[r], 8); ssr[r] += __shfl_xor(ssr[r], 8);
        }
        float mean2[4], rs2[4];
        #pragma unroll
        for (int r = 0; r < 4; ++r) {
            float m = sr[r] * (1.f / 256.f);
            float v = ssr[r] * (1.f / 256.f) - m * m;
            mean2[r] = m; rs2[r] = rsqrtf(v + 1e-5f);
        }
        // NO barrier: each wave reads and rewrites only its own sm_t rows.
        #pragma unroll
        for (int t2 = 0; t2 < 16; ++t2) {
            int col = t2 * 16 + n15;
            float pg = gload(postg, col, isf32), pb2 = gload(postb, col, isf32);
            #pragma unroll
            for (int r = 0; r < 4; ++r) {
                int tok = wv * 16 + quad * 4 + r;
                float o1 = accp[t2][r];
                float fin = o1 + (o1 - mean2[r]) * rs2[r] * pg + pb2;
                sm_t[tok * TP + col] = f2b(fin);
            }
        }
    }
    __syncthreads();   // store phase reads sm_t transposed (cross-wave)

    // ---- store (mirror of load) ----
    if (isf32) {
        float* outf = (float*)out;
        #pragma unroll
        for (int r = 0; r < 8; ++r) {
            int s = tid + r * 256;
            int c = s >> 3, i = s & 7;
            const u16* src = &sm_t[(i * 8) * TP + c];
            float* dst = outf + base + c * HWP + i * WW2;
            float4 a, d;
            a.x = b2f(src[0 * TP]); a.y = b2f(src[1 * TP]);
            a.z = b2f(src[2 * TP]); a.w = b2f(src[3 * TP]);
            d.x = b2f(src[4 * TP]); d.y = b2f(src[5 * TP]);
            d.z = b2f(src[6 * TP]); d.w = b2f(src[7 * TP]);
            *(float4_a*)dst = a;
            *(float4_a*)(dst + 4) = d;
        }
    } else {
        u16* outu = (u16*)out;
        #pragma unroll
        for (int r = 0; r < 8; ++r) {
            int s = tid + r * 256;
            int c = s >> 3, i = s & 7;
            const u16* src = &sm_t[(i * 8) * TP + c];
            uint4 v;
            v.x = (unsigned)src[0 * TP] | ((unsigned)src[1 * TP] << 16);
            v.y = (unsigned)src[2 * TP] | ((unsigned)src[3 * TP] << 16);
            v.z = (unsigned)src[4 * TP] | ((unsigned)src[5 * TP] << 16);
            v.w = (unsigned)src[6 * TP] | ((unsigned)src[7 * TP] << 16);
            *(uint4_a*)(outu + base + c * HWP + i * WW2) = v;
        }
    }
}

// ---------------------------------------------------------------------------
extern "C" void kernel_launch(void* const* d_in, const int* in_sizes, int n_in,
                              void* d_out, int out_size, void* d_ws, size_t ws_size,
                              hipStream_t stream) {
    const void* x     = d_in[0];
    const void* preg  = d_in[1];
    const void* preb  = d_in[2];
    const void* postg = d_in[3];
    const void* postb = d_in[4];
    const void* qkvw  = d_in[5];
    const void* qkvb  = d_in[6];
    const void* projw = d_in[7];
    const void* projb = d_in[8];
    const void* table = d_in[9];

    char* ws = (char*)d_ws;
    u16*   gwT = (u16*)(ws);                  // 768*256*2 = 393216
    u16*   pwT = (u16*)(ws + 393216);         // 256*256*2 = 131072  -> 524288
    float* D2  = (float*)(ws + 524288);       // 768*4 -> 527360
    float* D3  = (float*)(ws + 527360);       // 768*4 -> 530432
    float* tbf = (float*)(ws + 530432);       // 3600*4 = 14400 -> 544832
    int*   flg = (int*)(ws + 544832);         // 4 B

    detect_dtype<<<1, 64, 0, stream>>>((const u16*)x, flg);
    prep_qkv<<<768, 256, 0, stream>>>(qkvw, qkvb, preg, preb, gwT, D2, D3, flg);
    prep_proj<<<256, 256, 0, stream>>>(projw, pwT, table, tbf, flg);
    win_attn<<<NWIN, 256, 0, stream>>>(x, d_out, gwT, pwT, D2, D3,
                                       projb, postg, postb, tbf, flg);
}